// Round 12
// baseline (452.552 us; speedup 1.0000x reference)
//
#include <hip/hip_runtime.h>
#include <cstdint>

typedef short short8 __attribute__((ext_vector_type(8)));
typedef float f32x4 __attribute__((ext_vector_type(4)));

#define LDS_AS3(p) ((__attribute__((address_space(3))) unsigned*)(p))
#define GLB_AS1(p) ((const __attribute__((address_space(1))) unsigned*)(p))

// fp32 -> bf16 (round-to-nearest-even), two packed into a u32
__device__ inline unsigned bfpack(float a, float b) {
    union { float f; unsigned u; } ua, ub;
    ua.f = a; ub.f = b;
    unsigned lo = (ua.u + 0x7FFFu + ((ua.u >> 16) & 1u)) >> 16;
    unsigned hi = (ub.u + 0x7FFFu + ((ub.u >> 16) & 1u)) & 0xFFFF0000u;
    return lo | hi;
}
__device__ inline unsigned short bf16of(float a) { return (unsigned short)bfpack(a, 0.0f); }
__device__ inline float bf2f(unsigned short s) {
    union { unsigned u; float f; } x; x.u = (unsigned)s << 16; return x.f;
}

// ---------------- prepass: convert X to bf16 (same [.,448,512] layout) ------
__global__ __launch_bounds__(256)
void cvt_x(const float* __restrict__ X, unsigned short* __restrict__ XB)
{
    const int g = blockIdx.x * 256 + threadIdx.x;
    const float4 v0 = *(const float4*)(X + (size_t)g * 8);
    const float4 v1 = *(const float4*)(X + (size_t)g * 8 + 4);
    uint4 u;
    u.x = bfpack(v0.x, v0.y); u.y = bfpack(v0.z, v0.w);
    u.z = bfpack(v1.x, v1.y); u.w = bfpack(v1.z, v1.w);
    *(uint4*)(XB + (size_t)g * 8) = u;
}

// ------------- prepass: convert + transpose W[512][N] -> WT[N][512] bf16 ----
template <int N>
__global__ __launch_bounds__(256)
void cvt_w(const float* __restrict__ W, unsigned short* __restrict__ WT)
{
    const int g = blockIdx.x * 256 + threadIdx.x;
    if (g >= N * 64) return;
    const int n = g % N, d8 = g / N;
    const float* p = W + (size_t)d8 * 8 * N + n;
    uint4 u;
    u.x = bfpack(p[0],             p[(size_t)N]);
    u.y = bfpack(p[2 * (size_t)N], p[3 * (size_t)N]);
    u.z = bfpack(p[4 * (size_t)N], p[5 * (size_t)N]);
    u.w = bfpack(p[6 * (size_t)N], p[7 * (size_t)N]);
    *(uint4*)(WT + (size_t)n * 512 + d8 * 8) = u;
}

// ------- 256x256 GEMM, 1024 thr (16 waves, 4x4), BK=64 dbuf + scatter -------
// PROBE=0: real (R10 verbatim). PROBE=1: K-loop only, acc asm-sunk.
// PROBE=2: epilogue only, acc laundered (opaque zero). PROBE=3: laundered acc,
// same write volume as the epilogue but perfectly coalesced streaming stores.
// Probes run BEFORE the real kernels; every byte they scribble (Y, EXT1) is
// rewritten by the real fused kernels, so final output is unaffected.
template <int MODE, int PROBE>
__global__ __launch_bounds__(1024, 4)
void gemm_big(const unsigned short* __restrict__ XB,
              const unsigned short* __restrict__ WT,
              const float* __restrict__ BIAS, float* __restrict__ Y,
              const unsigned short* __restrict__ EXTI,
              unsigned short* __restrict__ EXTO)
{
    constexpr int K_L  = (MODE == 0) ? 64 : (MODE == 1) ? 128 : 256;
    constexpr int LOGK = (MODE == 0) ? 6  : (MODE == 1) ? 7   : 8;
    constexpr int N    = (MODE == 0) ? 1180 : (MODE == 1) ? 2881 : 1153;
    constexpr int XOFF = (MODE == 0) ? 0 : (MODE == 1) ? 64 : 192;
    constexpr int NT   = (N + 255) / 256;

    __shared__ __align__(16) unsigned short lA[2][256 * 64];   // 64 KB
    __shared__ __align__(16) unsigned short lB[2][256 * 64];   // 64 KB

    const int t    = threadIdx.x;            // 0..1023
    const int lane = t & 63;
    const int wv   = t >> 6;                 // 0..15
    const int wr   = wv >> 2;                // m wave 0..3
    const int wc   = wv & 3;                 // n wave 0..3
    const int kq   = lane >> 4;              // 0..3
    const int lr16 = lane & 15;

    // bijective XCD-chunk swizzle (grids divisible by 8); N-minor order
    const int cpx = (int)gridDim.x >> 3;
    const int wg  = (blockIdx.x & 7) * cpx + (blockIdx.x >> 3);
    const int nt  = wg % NT;
    const int mt  = wg / NT;
    const int m0  = mt * 256;
    const int n0  = nt * 256;

    auto stage = [&](int buf, int kt) {
        #pragma unroll
        for (int i = 0; i < 2; ++i) {
            const int c   = i * 1024 + t;            // 0..2047
            const int row = c >> 3, p = c & 7, l = p ^ (row & 7);
            const int m   = m0 + row;
            const int b   = m >> LOGK, kd = m & (K_L - 1);
            const unsigned short* gp =
                XB + ((size_t)(b * 448 + XOFF + kd) << 9) + kt * 64 + l * 8;
            __builtin_amdgcn_global_load_lds(GLB_AS1(gp),
                LDS_AS3(&lA[buf][c * 8]), 16, 0, 0);
        }
        #pragma unroll
        for (int i = 0; i < 2; ++i) {
            const int c   = i * 1024 + t;
            const int row = c >> 3, p = c & 7, l = p ^ (row & 7);
            int gc = n0 + row; if (gc > N - 1) gc = N - 1;   // N-tail clamp
            const unsigned short* gp = WT + (size_t)gc * 512 + kt * 64 + l * 8;
            __builtin_amdgcn_global_load_lds(GLB_AS1(gp),
                LDS_AS3(&lB[buf][c * 8]), 16, 0, 0);
        }
    };

    f32x4 acc[4][4] = {};

    if constexpr (PROBE == 2 || PROBE == 3) {
        // opaque zero: epilogue cannot be const-folded (rule #17)
        float z0;
        asm volatile("v_mov_b32 %0, 0" : "=v"(z0));
        #pragma unroll
        for (int mi = 0; mi < 4; ++mi)
            #pragma unroll
            for (int ni = 0; ni < 4; ++ni) {
                f32x4 z = {z0, z0, z0, z0};
                acc[mi][ni] = z;
            }
    }

    if constexpr (PROBE <= 1) {
        // ---- prologue + K loop (R10 verbatim) -----------------------------
        stage(0, 0);
        __syncthreads();
        #pragma unroll 1
        for (int kt = 0; kt < 8; ++kt) {
            const int buf = kt & 1;
            if (kt < 7) stage(buf ^ 1, kt + 1);
            #pragma unroll
            for (int ks = 0; ks < 2; ++ks) {
                const int s = ks * 4 + kq;
                short8 af[4], bf[4];
                #pragma unroll
                for (int mi = 0; mi < 4; ++mi) {
                    const int row = wr * 64 + mi * 16 + lr16;
                    af[mi] = *(const short8*)(&lA[buf][row * 64 + ((s ^ (row & 7)) * 8)]);
                }
                #pragma unroll
                for (int ni = 0; ni < 4; ++ni) {
                    const int row = wc * 64 + ni * 16 + lr16;
                    bf[ni] = *(const short8*)(&lB[buf][row * 64 + ((s ^ (row & 7)) * 8)]);
                }
                __builtin_amdgcn_s_setprio(1);
                #pragma unroll
                for (int mi = 0; mi < 4; ++mi)
                    #pragma unroll
                    for (int ni = 0; ni < 4; ++ni)
                        acc[mi][ni] = __builtin_amdgcn_mfma_f32_16x16x32_bf16(
                            af[mi], bf[ni], acc[mi][ni], 0, 0, 0);
                __builtin_amdgcn_s_setprio(0);
            }
            __syncthreads();
        }
    }

    if constexpr (PROBE == 1) {
        // keep all MFMAs live, no stores
        f32x4 s = acc[0][0];
        #pragma unroll
        for (int mi = 0; mi < 4; ++mi)
            #pragma unroll
            for (int ni = 0; ni < 4; ++ni)
                if (mi || ni) s += acc[mi][ni];
        asm volatile("" :: "v"(s[0]), "v"(s[1]), "v"(s[2]), "v"(s[3]));
        return;
    }

    if constexpr (PROBE == 3) {
        // same write volume as the scatter epilogue (~128B/thread bf16-packed)
        // but perfectly coalesced: per instr, 1024 consecutive uint4.
        uint4 q;
        q.x = bfpack(acc[0][0][0], acc[0][0][1]);
        q.y = bfpack(acc[0][0][2], acc[0][0][3]);
        q.z = bfpack(acc[1][1][0], acc[1][1][1]);
        q.w = bfpack(acc[2][2][0], acc[2][2][1]);
        uint4* y4 = (uint4*)Y;                     // scribble; rewritten later
        const size_t base = (size_t)wg * 8192;
        #pragma unroll
        for (int i = 0; i < 8; ++i)
            y4[base + (size_t)i * 1024 + t] = q;
        return;
    }

    // ---- epilogue: bias + closed-form scatter (R10 verbatim) --------------
    #pragma unroll
    for (int ni = 0; ni < 4; ++ni) {
        const int n = n0 + wc * 64 + ni * 16 + lr16;
        if (n >= N) continue;
        const float bias = BIAS[n];
        #pragma unroll
        for (int mi = 0; mi < 4; ++mi) {
            #pragma unroll
            for (int r = 0; r < 4; ++r) {
                const int m  = m0 + wr * 64 + mi * 16 + kq * 4 + r;
                const int b  = m >> LOGK;
                const int kd = m & (K_L - 1);
                const float v = acc[mi][ni][r] + bias;
                float* yb = Y + (size_t)b * 370816;
                if constexpr (MODE == 0) {
                    if (n < 27)       yb[kd * 27 + n] = v;
                    else if (n == 27) yb[1728 + kd]   = v;
                    else EXTO[((size_t)(b * 64 + kd)) * 1152 + (n - 28)] = bf16of(v);
                } else if constexpr (MODE == 1) {
                    if (n < 576) {
                        const float e = bf2f(EXTI[((size_t)(b * 64 + n / 9)) * 1152 + kd * 9 + n % 9]);
                        yb[1792 + kd * 576 + n] = 0.5f * (v + e);
                    } else if (n == 576) yb[75520 + kd] = 0.5f * v;
                    else EXTO[((size_t)(b * 128 + kd)) * 2304 + (n - 577)] = bf16of(v);
                } else {
                    if (n < 1152) {
                        const float e = bf2f(EXTI[((size_t)(b * 128 + n / 9)) * 2304 + kd * 9 + n % 9]);
                        yb[75648 + kd * 1152 + n] = v + e;
                    } else yb[370560 + kd] = v;
                }
            }
        }
    }
}

extern "C" void kernel_launch(void* const* d_in, const int* in_sizes, int n_in,
                              void* d_out, int out_size, void* d_ws, size_t ws_size,
                              hipStream_t stream)
{
    const float* x  = (const float*)d_in[0];
    const float* W0 = (const float*)d_in[1];
    const float* b0 = (const float*)d_in[2];
    const float* W1 = (const float*)d_in[3];
    const float* b1 = (const float*)d_in[4];
    const float* W2 = (const float*)d_in[5];
    const float* b2 = (const float*)d_in[6];
    float* y = (float*)d_out;

    // ws (bf16): XB[128*448*512] | WT0 | WT1 | WT2 | EXT0[128*64*1152] | EXT1[128*128*2304]
    unsigned short* XB   = (unsigned short*)d_ws;
    unsigned short* WT0  = XB   + (size_t)128 * 448 * 512;
    unsigned short* WT1  = WT0  + (size_t)1180 * 512;
    unsigned short* WT2  = WT1  + (size_t)2881 * 512;
    unsigned short* EXT0 = WT2  + (size_t)1153 * 512;
    unsigned short* EXT1 = EXT0 + (size_t)128 * 64 * 1152;

    cvt_x<<<dim3(14336), 256, 0, stream>>>(x, XB);
    cvt_w<1180><<<dim3((1180 * 64 + 255) / 256), 256, 0, stream>>>(W0, WT0);
    cvt_w<2881><<<dim3((2881 * 64 + 255) / 256), 256, 0, stream>>>(W1, WT1);
    cvt_w<1153><<<dim3((1153 * 64 + 255) / 256), 256, 0, stream>>>(W2, WT2);

    // ---- probes (L1 shape). Scribbles on Y/EXT1 are fully overwritten by
    // the real fused kernels below; final output is byte-identical.
    gemm_big<1, 1><<<dim3(64 * 12), 1024, 0, stream>>>(XB, WT1, b1, y, EXT0, EXT1);
    gemm_big<1, 2><<<dim3(64 * 12), 1024, 0, stream>>>(XB, WT1, b1, y, EXT0, EXT1);
    gemm_big<1, 3><<<dim3(64 * 12), 1024, 0, stream>>>(XB, WT1, b1, y, EXT0, EXT1);

    // ---- real kernels (R10 verbatim); stream order = EXT dependency -------
    gemm_big<0, 0><<<dim3(32 * 5),  1024, 0, stream>>>(XB, WT0, b0, y, nullptr, EXT0);
    gemm_big<1, 0><<<dim3(64 * 12), 1024, 0, stream>>>(XB, WT1, b1, y, EXT0, EXT1);
    gemm_big<2, 0><<<dim3(128 * 5), 1024, 0, stream>>>(XB, WT2, b2, y, EXT1, nullptr);
}

// Round 13
// 293.854 us; speedup vs baseline: 1.5401x; 1.5401x over previous
//
#include <hip/hip_runtime.h>
#include <cstdint>

typedef short short8 __attribute__((ext_vector_type(8)));
typedef float f32x4 __attribute__((ext_vector_type(4)));

#define LDS_AS3(p) ((__attribute__((address_space(3))) unsigned*)(p))
#define GLB_AS1(p) ((const __attribute__((address_space(1))) unsigned*)(p))

// fp32 -> bf16 (round-to-nearest-even), two packed into a u32
__device__ inline unsigned bfpack(float a, float b) {
    union { float f; unsigned u; } ua, ub;
    ua.f = a; ub.f = b;
    unsigned lo = (ua.u + 0x7FFFu + ((ua.u >> 16) & 1u)) >> 16;
    unsigned hi = (ub.u + 0x7FFFu + ((ub.u >> 16) & 1u)) & 0xFFFF0000u;
    return lo | hi;
}
__device__ inline unsigned short bf16of(float a) { return (unsigned short)bfpack(a, 0.0f); }
__device__ inline float bf2f(unsigned short s) {
    union { unsigned u; float f; } x; x.u = (unsigned)s << 16; return x.f;
}

constexpr int E1S = 2308;   // EXT1 row stride (shorts); col = n-576 (8B-aligned runs)

// ---------------- prepass: convert X to bf16 (same [.,448,512] layout) ------
__global__ __launch_bounds__(256)
void cvt_x(const float* __restrict__ X, unsigned short* __restrict__ XB)
{
    const int g = blockIdx.x * 256 + threadIdx.x;
    const float4 v0 = *(const float4*)(X + (size_t)g * 8);
    const float4 v1 = *(const float4*)(X + (size_t)g * 8 + 4);
    uint4 u;
    u.x = bfpack(v0.x, v0.y); u.y = bfpack(v0.z, v0.w);
    u.z = bfpack(v1.x, v1.y); u.w = bfpack(v1.z, v1.w);
    *(uint4*)(XB + (size_t)g * 8) = u;
}

// ------------- prepass: convert + transpose W[512][N] -> WT[N][512] bf16 ----
template <int N>
__global__ __launch_bounds__(256)
void cvt_w(const float* __restrict__ W, unsigned short* __restrict__ WT)
{
    const int g = blockIdx.x * 256 + threadIdx.x;
    if (g >= N * 64) return;
    const int n = g % N, d8 = g / N;
    const float* p = W + (size_t)d8 * 8 * N + n;
    uint4 u;
    u.x = bfpack(p[0],             p[(size_t)N]);
    u.y = bfpack(p[2 * (size_t)N], p[3 * (size_t)N]);
    u.z = bfpack(p[4 * (size_t)N], p[5 * (size_t)N]);
    u.w = bfpack(p[6 * (size_t)N], p[7 * (size_t)N]);
    *(uint4*)(WT + (size_t)n * 512 + d8 * 8) = u;
}

// ------- 256x256 GEMM (R10 K-loop) + COALESCED LDS-transpose epilogue -------
// R11 probes: epilogue-only ~= full kernel time; coalesced-same-volume ~6x
// faster. So: after the K-loop, acc -> LDS f32 [rows][260] (passes fit 130KB),
// then row-streaming: each wave owns full (b,kd) rows -> Y own-region written
// as 1KB float4 runs, EXT as 8B-aligned uint2 bf16 runs (no 32B-segment
// amplification). MODE2 gathers EXT1 via an LDS panel (coalesced panel loads)
// instead of 18B-granular global reads. Mixed/tail strips: scalar fallback.
template <int MODE>
__global__ __launch_bounds__(1024, 4)
void gemm_big(const unsigned short* __restrict__ XB,
              const unsigned short* __restrict__ WT,
              const float* __restrict__ BIAS, float* __restrict__ Y,
              const unsigned short* __restrict__ EXTI,
              unsigned short* __restrict__ EXTO)
{
    constexpr int K_L  = (MODE == 0) ? 64 : (MODE == 1) ? 128 : 256;
    constexpr int LOGK = (MODE == 0) ? 6  : (MODE == 1) ? 7   : 8;
    constexpr int N    = (MODE == 0) ? 1180 : (MODE == 1) ? 2881 : 1153;
    constexpr int XOFF = (MODE == 0) ? 0 : (MODE == 1) ? 64 : 192;
    constexpr int NT   = (N + 255) / 256;

    __shared__ __align__(16) char smem[133120];          // K-loop 128KB / epi 130KB
    unsigned short* lAp = (unsigned short*)smem;          // [2][256*64]
    unsigned short* lBp = lAp + 2 * 256 * 64;             // [2][256*64]

    const int t    = threadIdx.x;            // 0..1023
    const int lane = t & 63;
    const int wv   = t >> 6;                 // 0..15
    const int wr   = wv >> 2;                // m wave 0..3
    const int wc   = wv & 3;                 // n wave 0..3
    const int kq   = lane >> 4;              // 0..3
    const int lr16 = lane & 15;

    // bijective XCD-chunk swizzle (grids divisible by 8); N-minor order
    const int cpx = (int)gridDim.x >> 3;
    const int wg  = (blockIdx.x & 7) * cpx + (blockIdx.x >> 3);
    const int nt  = wg % NT;
    const int mt  = wg / NT;
    const int m0  = mt * 256;
    const int n0  = nt * 256;

    auto stage = [&](int buf, int kt) {
        #pragma unroll
        for (int i = 0; i < 2; ++i) {
            const int c   = i * 1024 + t;            // 0..2047
            const int row = c >> 3, p = c & 7, l = p ^ (row & 7);
            const int m   = m0 + row;
            const int b   = m >> LOGK, kd = m & (K_L - 1);
            const unsigned short* gp =
                XB + ((size_t)(b * 448 + XOFF + kd) << 9) + kt * 64 + l * 8;
            __builtin_amdgcn_global_load_lds(GLB_AS1(gp),
                LDS_AS3(lAp + buf * 16384 + c * 8), 16, 0, 0);
        }
        #pragma unroll
        for (int i = 0; i < 2; ++i) {
            const int c   = i * 1024 + t;
            const int row = c >> 3, p = c & 7, l = p ^ (row & 7);
            int gc = n0 + row; if (gc > N - 1) gc = N - 1;   // N-tail clamp
            const unsigned short* gp = WT + (size_t)gc * 512 + kt * 64 + l * 8;
            __builtin_amdgcn_global_load_lds(GLB_AS1(gp),
                LDS_AS3(lBp + buf * 16384 + c * 8), 16, 0, 0);
        }
    };

    f32x4 acc[4][4] = {};

    // ---- K loop (R10 verbatim): stage(next) -> compute(cur) -> sync -------
    stage(0, 0);
    __syncthreads();
    #pragma unroll 1
    for (int kt = 0; kt < 8; ++kt) {
        const int buf = kt & 1;
        if (kt < 7) stage(buf ^ 1, kt + 1);
        #pragma unroll
        for (int ks = 0; ks < 2; ++ks) {
            const int s = ks * 4 + kq;
            short8 af[4], bf[4];
            #pragma unroll
            for (int mi = 0; mi < 4; ++mi) {
                const int row = wr * 64 + mi * 16 + lr16;
                af[mi] = *(const short8*)(lAp + buf * 16384 + row * 64 + ((s ^ (row & 7)) * 8));
            }
            #pragma unroll
            for (int ni = 0; ni < 4; ++ni) {
                const int row = wc * 64 + ni * 16 + lr16;
                bf[ni] = *(const short8*)(lBp + buf * 16384 + row * 64 + ((s ^ (row & 7)) * 8));
            }
            __builtin_amdgcn_s_setprio(1);
            #pragma unroll
            for (int mi = 0; mi < 4; ++mi)
                #pragma unroll
                for (int ni = 0; ni < 4; ++ni)
                    acc[mi][ni] = __builtin_amdgcn_mfma_f32_16x16x32_bf16(
                        af[mi], bf[ni], acc[mi][ni], 0, 0, 0);
            __builtin_amdgcn_s_setprio(0);
        }
        __syncthreads();
    }

    // ================= coalesced epilogue =================
    constexpr int RPP   = (MODE == 2) ? 64 : 128;     // rows per pass
    constexpr int NPASS = 256 / RPP;
    constexpr int RPW   = RPP / 16;                   // rows per wave
    float* LDSf = (float*)smem;                       // [RPP][260]
    unsigned short* panel = (unsigned short*)(smem + 66560);  // MODE2 only

    // strip class: 0 = pure-own vector, 1 = pure-ext vector, 2 = scalar
    const int cls = (MODE == 0) ? ((n0 == 0 || n0 + 255 >= N) ? 2 : 1)
                  : (MODE == 1) ? ((n0 + 255 < 576) ? 0 : (n0 <= 576) ? 2
                                   : (n0 + 255 < N) ? 1 : 2)
                  :               ((n0 + 255 < 1152) ? 0 : 2);

    #pragma unroll 1
    for (int h = 0; h < NPASS; ++h) {
        if (h) __syncthreads();                       // prev pass readers done
        const bool mine = (MODE == 2) ? (wr == h) : ((wr >> 1) == h);
        if (mine) {
            const int mb = (MODE == 2) ? 0 : (wr & 1) * 64;
            #pragma unroll
            for (int mi = 0; mi < 4; ++mi)
                #pragma unroll
                for (int ni = 0; ni < 4; ++ni)
                    #pragma unroll
                    for (int r = 0; r < 4; ++r)
                        LDSf[(mb + mi * 16 + kq * 4 + r) * 260 + wc * 64 + ni * 16 + lr16]
                            = acc[mi][ni][r];
        }
        int row_lo = 0;
        if constexpr (MODE == 2) {                    // load E1 panel (coalesced)
            row_lo = n0 / 9;
            const int ntop  = (n0 + 256 <= 1152) ? (n0 + 255) : 1151;
            const int nrows = ntop / 9 - row_lo + 1;
            const int col0  = h * 576;
            const int bB    = m0 >> 8;
            for (int t2 = t; t2 < nrows * 145; t2 += 1024) {
                const int rr2 = t2 / 145, cc = t2 % 145;
                const uint2 v = *(const uint2*)(EXTI +
                    ((size_t)(bB * 128 + row_lo + rr2)) * E1S + col0 + cc * 4);
                *(uint2*)(panel + rr2 * 584 + cc * 4) = v;
            }
        }
        __syncthreads();

        // row streaming: wave owns whole output rows -> long contiguous runs
        #pragma unroll 1
        for (int rr = 0; rr < RPW; ++rr) {
            const int ml = wv * RPW + rr;
            const int m  = m0 + h * RPP + ml;
            const int b  = m >> LOGK;
            const int kd = m & (K_L - 1);
            const int nb = n0 + lane * 4;
            const float4 v4 = *(const float4*)&LDSf[ml * 260 + lane * 4];
            float* yb = Y + (size_t)b * 370816;

            if (cls == 0) {                           // pure own (MODE1/2)
                const float4 b4 = *(const float4*)(BIAS + nb);
                float e[4];
                if constexpr (MODE == 1) {
                    #pragma unroll
                    for (int i = 0; i < 4; ++i) {
                        const int n = nb + i;
                        e[i] = bf2f(EXTI[((size_t)(b * 64 + n / 9)) * 1152 + kd * 9 + n % 9]);
                    }
                    float4 o;
                    o.x = 0.5f * (v4.x + b4.x + e[0]); o.y = 0.5f * (v4.y + b4.y + e[1]);
                    o.z = 0.5f * (v4.z + b4.z + e[2]); o.w = 0.5f * (v4.w + b4.w + e[3]);
                    *(float4*)(yb + 1792 + kd * 576 + nb) = o;
                } else {
                    #pragma unroll
                    for (int i = 0; i < 4; ++i) {
                        const int n = nb + i;
                        e[i] = bf2f(panel[(n / 9 - row_lo) * 584 + ml * 9 + n % 9 + 1]);
                    }
                    float4 o;
                    o.x = v4.x + b4.x + e[0]; o.y = v4.y + b4.y + e[1];
                    o.z = v4.z + b4.z + e[2]; o.w = v4.w + b4.w + e[3];
                    *(float4*)(yb + 75648 + kd * 1152 + nb) = o;
                }
            } else if (cls == 1) {                    // pure ext (MODE0/1)
                const float4 b4 = *(const float4*)(BIAS + nb);
                uint2 u;
                u.x = bfpack(v4.x + b4.x, v4.y + b4.y);
                u.y = bfpack(v4.z + b4.z, v4.w + b4.w);
                if constexpr (MODE == 0)
                    *(uint2*)(EXTO + ((size_t)(b * 64 + kd)) * 1152 + (nb - 28)) = u;
                else
                    *(uint2*)(EXTO + ((size_t)(b * 128 + kd)) * E1S + (nb - 576)) = u;
            } else {                                  // mixed / tail: scalar
                #pragma unroll
                for (int i = 0; i < 4; ++i) {
                    const int n = nb + i;
                    if (n >= N) continue;
                    const float v = ((const float*)&v4)[i] + BIAS[n];
                    if constexpr (MODE == 0) {
                        if (n < 27)       yb[kd * 27 + n] = v;
                        else if (n == 27) yb[1728 + kd]   = v;
                        else EXTO[((size_t)(b * 64 + kd)) * 1152 + (n - 28)] = bf16of(v);
                    } else if constexpr (MODE == 1) {
                        if (n < 576) {
                            const float e = bf2f(EXTI[((size_t)(b * 64 + n / 9)) * 1152 + kd * 9 + n % 9]);
                            yb[1792 + kd * 576 + n] = 0.5f * (v + e);
                        } else if (n == 576) yb[75520 + kd] = 0.5f * v;
                        else EXTO[((size_t)(b * 128 + kd)) * E1S + (n - 576)] = bf16of(v);
                    } else {
                        if (n < 1152) {
                            const float e = bf2f(panel[(n / 9 - row_lo) * 584 + ml * 9 + n % 9 + 1]);
                            yb[75648 + kd * 1152 + n] = v + e;
                        } else if (n == 1152) yb[370560 + kd] = v;
                    }
                }
            }
        }
    }
}

extern "C" void kernel_launch(void* const* d_in, const int* in_sizes, int n_in,
                              void* d_out, int out_size, void* d_ws, size_t ws_size,
                              hipStream_t stream)
{
    const float* x  = (const float*)d_in[0];
    const float* W0 = (const float*)d_in[1];
    const float* b0 = (const float*)d_in[2];
    const float* W1 = (const float*)d_in[3];
    const float* b1 = (const float*)d_in[4];
    const float* W2 = (const float*)d_in[5];
    const float* b2 = (const float*)d_in[6];
    float* y = (float*)d_out;

    // ws (bf16): XB | WT0 | WT1 | WT2 | EXT0[8192*1152] | EXT1[16384*2308]
    unsigned short* XB   = (unsigned short*)d_ws;
    unsigned short* WT0  = XB   + (size_t)128 * 448 * 512;
    unsigned short* WT1  = WT0  + (size_t)1180 * 512;
    unsigned short* WT2  = WT1  + (size_t)2881 * 512;
    unsigned short* EXT0 = WT2  + (size_t)1153 * 512;
    unsigned short* EXT1 = EXT0 + (size_t)128 * 64 * 1152;

    cvt_x<<<dim3(14336), 256, 0, stream>>>(x, XB);
    cvt_w<1180><<<dim3((1180 * 64 + 255) / 256), 256, 0, stream>>>(W0, WT0);
    cvt_w<2881><<<dim3((2881 * 64 + 255) / 256), 256, 0, stream>>>(W1, WT1);
    cvt_w<1153><<<dim3((1153 * 64 + 255) / 256), 256, 0, stream>>>(W2, WT2);

    // grids: (M/256) * ceil(N/256); all divisible by 8; stream order = EXT dep
    gemm_big<0><<<dim3(32 * 5),  1024, 0, stream>>>(XB, WT0, b0, y, nullptr, EXT0);
    gemm_big<1><<<dim3(64 * 12), 1024, 0, stream>>>(XB, WT1, b1, y, EXT0, EXT1);
    gemm_big<2><<<dim3(128 * 5), 1024, 0, stream>>>(XB, WT2, b2, y, EXT1, nullptr);
}